// Round 9
// baseline (33.926 us; speedup 1.0000x reference)
//
#include <hip/hip_runtime.h>

#define NB 8
#define NP 16
#define NS 256
#define NN 4096
#define NBP (NB*NP)             // 128
#define NCHUNK 16
#define CHUNK (NN/NCHUNK)       // 256 n per block
#define NBLK (NBP*NCHUNK)       // 2048
#define EPSV 1e-6f

typedef float f32x2 __attribute__((ext_vector_type(2)));

__device__ __forceinline__ f32x2 pkfma(f32x2 a, f32x2 b, f32x2 c) {
    f32x2 d;
    asm("v_pk_fma_f32 %0, %1, %2, %3" : "=v"(d) : "v"(a), "v"(b), "v"(c));
    return d;
}
__device__ __forceinline__ f32x2 sp2(float v) { return (f32x2){v, v}; }

// ---------------- workspace layout (bytes) ----------------
// minw : float[NBLK*NS]  @ 0          (2 MB)
// part : float[NBLK]     @ 0x200000   (8 KB)
// s2p  : float[NBP]      @ 0x202000
// pp   : float[NBP]      @ 0x202400

__global__ __launch_bounds__(256) void sqreg_main(
    const float* __restrict__ sp,     // (B,P,S,3)
    const float* __restrict__ pts,    // (B,N,3)
    const float* __restrict__ assign, // (B,N,P)
    float* __restrict__ minw,         // (NBLK, S)
    float* __restrict__ partials)     // NBLK
{
    // SoA staging; s/n pairs load as ds_read_b64 feeding v_pk_fma_f32
    __shared__ __align__(16) float lspx[NS], lspy[NS], lspz[NS], lspw[NS];       // a, |a|^2
    __shared__ __align__(16) float lptx[CHUNK], lpty[CHUNK], lptz[CHUNK], lptw[CHUNK]; // -2b, |b|^2
    __shared__ float pm1[4][CHUNK];   // phase-1 partial mins (s-quarter, n)
    __shared__ float pm2[8][NS];      // phase-2 partial mins (n-eighth, s)
    __shared__ float psum[4];

    const int bid   = blockIdx.x;
    const int bp    = bid >> 4;       // 0..127
    const int chunk = bid & 15;
    const int p     = bp & 15;
    const int b     = bp >> 4;
    const int tid   = threadIdx.x;
    const int lane  = tid & 63;
    const int wave  = tid >> 6;

    // ---- stage + prescale (SoA): 1 s and 1 n per thread ----
    {
        const float* s3 = sp + (size_t)(bp*NS)*3;
        float x = s3[tid*3+0], y = s3[tid*3+1], z = s3[tid*3+2];
        lspx[tid] = x; lspy[tid] = y; lspz[tid] = z;
        lspw[tid] = x*x + y*y + z*z;
        const float* q3 = pts + (size_t)(b*NN + chunk*CHUNK)*3;
        float qx = q3[tid*3+0], qy = q3[tid*3+1], qz = q3[tid*3+2];
        lptx[tid] = -2.0f*qx; lpty[tid] = -2.0f*qy; lptz[tid] = -2.0f*qz;
        lptw[tid] = qx*qx + qy*qy + qz*qz;
    }
    __syncthreads();

    // ---- Phase 1: s-quarter split (g==wave), 4 n/thread; min over 64 s of (a2-2ab) ----
    {
        const int g  = tid >> 6;       // wave-uniform -> broadcast b64 reads
        const int nl = tid & 63;
        f32x2 qx[4], qy[4], qz[4];
        float mn[4];
#pragma unroll
        for (int k = 0; k < 4; ++k) {
            int i = nl + k*64;
            qx[k] = sp2(lptx[i]); qy[k] = sp2(lpty[i]); qz[k] = sp2(lptz[i]);
            mn[k] = INFINITY;
        }
        const int sb = g*64;
#pragma unroll 2
        for (int s = 0; s < 64; s += 2) {
            f32x2 vx = *(const f32x2*)&lspx[sb+s];
            f32x2 vy = *(const f32x2*)&lspy[sb+s];
            f32x2 vz = *(const f32x2*)&lspz[sb+s];
            f32x2 vw = *(const f32x2*)&lspw[sb+s];
#pragma unroll
            for (int k = 0; k < 4; ++k) {
                f32x2 gg = pkfma(qx[k], vx, pkfma(qy[k], vy, pkfma(qz[k], vz, vw)));
                mn[k] = fminf(fminf(gg.x, gg.y), mn[k]);   // v_min3_f32
            }
        }
#pragma unroll
        for (int k = 0; k < 4; ++k) pm1[g][nl + k*64] = mn[k];
    }

    // ---- Phase 2: 8 s/thread, n-eighth split; min over 32 n of (b2-2ab) ----
    {
        const int sg   = tid & 31;
        const int nsub = tid >> 5;     // 0..7 (2 addrs per wave -> free 2-way bcast)
        f32x2 ax[8], ay[8], az[8];
        float m[8];
#pragma unroll
        for (int j = 0; j < 8; ++j) {
            int s = sg + j*32;
            ax[j] = sp2(lspx[s]); ay[j] = sp2(lspy[s]); az[j] = sp2(lspz[s]);
            m[j] = INFINITY;
        }
        const int nb = nsub*32;
#pragma unroll 2
        for (int n = 0; n < 32; n += 2) {
            f32x2 ux = *(const f32x2*)&lptx[nb+n];
            f32x2 uy = *(const f32x2*)&lpty[nb+n];
            f32x2 uz = *(const f32x2*)&lptz[nb+n];
            f32x2 uw = *(const f32x2*)&lptw[nb+n];
#pragma unroll
            for (int j = 0; j < 8; ++j) {
                f32x2 gg = pkfma(ux, ax[j], pkfma(uy, ay[j], pkfma(uz, az[j], uw)));
                m[j] = fminf(fminf(gg.x, gg.y), m[j]);     // v_min3_f32
            }
        }
#pragma unroll
        for (int j = 0; j < 8; ++j) pm2[nsub][sg + j*32] = m[j];
    }
    __syncthreads();

    // ---- combine phase 2 -> minw (s = tid) ----
    {
        float mm = fminf(fminf(fminf(pm2[0][tid], pm2[1][tid]),
                               fminf(pm2[2][tid], pm2[3][tid])),
                         fminf(fminf(pm2[4][tid], pm2[5][tid]),
                               fminf(pm2[6][tid], pm2[7][tid])));
        minw[(size_t)bid*NS + tid] = fmaxf(mm + lspw[tid], 0.0f);
    }

    // ---- combine phase 1 -> weighted partial (1 n per thread) ----
    float acc;
    {
        float mm = fminf(fminf(pm1[0][tid], pm1[1][tid]),
                         fminf(pm1[2][tid], pm1[3][tid]));
        float d  = fmaxf(mm + lptw[tid], 0.0f);
        acc = d * assign[(size_t)(b*NN + chunk*CHUNK + tid)*NP + p];
    }
#pragma unroll
    for (int msk = 32; msk >= 1; msk >>= 1)
        acc += __shfl_xor(acc, msk, 64);
    if (lane == 0) psum[wave] = acc;
    __syncthreads();
    if (tid == 0) partials[bid] = psum[0] + psum[1] + psum[2] + psum[3];
}

__global__ __launch_bounds__(256) void sqreg_tail(
    const float* __restrict__ minw,     // (NBLK, S)
    const float* __restrict__ partials, // NBLK
    float* __restrict__ s2p,            // NBP
    float* __restrict__ pp)             // NBP
{
    __shared__ float wsum[4];
    const int bp   = blockIdx.x;
    const int tid  = threadIdx.x;
    const int lane = tid & 63;
    const int wave = tid >> 6;

    const float* base = minw + (size_t)(bp*NCHUNK)*NS + tid;
    float m = base[0];
#pragma unroll
    for (int c = 1; c < NCHUNK; ++c) m = fminf(m, base[(size_t)c*NS]);
#pragma unroll
    for (int msk = 32; msk >= 1; msk >>= 1)
        m += __shfl_xor(m, msk, 64);
    if (lane == 0) wsum[wave] = m;
    __syncthreads();

    if (tid == 0) {
        s2p[bp] = (wsum[0] + wsum[1] + wsum[2] + wsum[3]) * (1.0f/(float)NS);
        float a = 0.0f;
#pragma unroll
        for (int c = 0; c < NCHUNK; ++c) a += partials[bp*NCHUNK + c];
        pp[bp] = a;
    }
}

__global__ __launch_bounds__(256) void sqreg_final(
    const float* __restrict__ s2p,
    const float* __restrict__ pp,
    const float* __restrict__ exist,   // (B,P)
    float* __restrict__ out)
{
    __shared__ float ppw[2];
    __shared__ float fin[8];
    const int tid = threadIdx.x;

    float tsum = (tid < NBP) ? pp[tid] : 0.0f;
#pragma unroll
    for (int msk = 32; msk >= 1; msk >>= 1)
        tsum += __shfl_xor(tsum, msk, 64);
    if (tid == 0)  ppw[0] = tsum;
    if (tid == 64) ppw[1] = tsum;

    if (tid < NBP) {                   // group of 16 lanes = one b
        float e  = exist[tid];
        float sv = s2p[tid] * e;
#pragma unroll
        for (int msk = 8; msk >= 1; msk >>= 1) {
            e  += __shfl_xor(e,  msk, 64);
            sv += __shfl_xor(sv, msk, 64);
        }
        if ((tid & 15) == 0) fin[tid >> 4] = sv / fmaxf(e, EPSV);
    }
    __syncthreads();

    if (tid == 0) {
        float sq = 0.0f;
#pragma unroll
        for (int g = 0; g < NB; ++g) sq += fin[g];
        out[0] = (ppw[0] + ppw[1]) / (float)(NB*NN) + sq * (1.0f/(float)NB);
    }
}

extern "C" void kernel_launch(void* const* d_in, const int* in_sizes, int n_in,
                              void* d_out, int out_size, void* d_ws, size_t ws_size,
                              hipStream_t stream) {
    const float* sp     = (const float*)d_in[0];
    const float* pts    = (const float*)d_in[1];
    const float* assign = (const float*)d_in[2];
    const float* exist  = (const float*)d_in[3];
    float* out = (float*)d_out;

    char* ws = (char*)d_ws;
    float* minw = (float*)(ws);
    float* part = (float*)(ws + 0x200000);
    float* s2p  = (float*)(ws + 0x202000);
    float* pp   = (float*)(ws + 0x202400);

    sqreg_main <<<NBLK, 256, 0, stream>>>(sp, pts, assign, minw, part);
    sqreg_tail <<<NBP,  256, 0, stream>>>(minw, part, s2p, pp);
    sqreg_final<<<1,    256, 0, stream>>>(s2p, pp, exist, out);
}

// Round 10
// 33.106 us; speedup vs baseline: 1.0248x; 1.0248x over previous
//
#include <hip/hip_runtime.h>

#define NB 8
#define NP 16
#define NS 256
#define NN 4096
#define NBP (NB*NP)             // 128
#define NCHUNK 8
#define CHUNK (NN/NCHUNK)       // 512 n per block
#define NBLK (NBP*NCHUNK)       // 1024
#define EPSV 1e-6f

typedef float f32x2 __attribute__((ext_vector_type(2)));

__device__ __forceinline__ f32x2 pkfma(f32x2 a, f32x2 b, f32x2 c) {
    return __builtin_elementwise_fma(a, b, c);
}
__device__ __forceinline__ f32x2 sp2(float v) { return (f32x2){v, v}; }

// ---------------- workspace layout (bytes) ----------------
// minw : float[NBLK*NS]  @ 0          (1 MB)
// part : float[NBLK]     @ 0x100000
// s2p  : float[NBP]      @ 0x101000
// pp   : float[NBP]      @ 0x101200
// cnt  : uint            @ 0x101400   (reset-free mod-128 gate)

__global__ __launch_bounds__(256) void sqreg_main(
    const float* __restrict__ sp,     // (B,P,S,3)
    const float* __restrict__ pts,    // (B,N,3)
    const float* __restrict__ assign, // (B,N,P)
    float* __restrict__ minw,         // (NBLK, S)
    float* __restrict__ partials)     // NBLK
{
    __shared__ __align__(16) float lspx[NS], lspy[NS], lspz[NS], lspw[NS];
    __shared__ __align__(16) float lptx[CHUNK], lpty[CHUNK], lptz[CHUNK], lptw[CHUNK];
    __shared__ float pm1[4][CHUNK];
    __shared__ float pm2[8][NS];
    __shared__ float psum[4];

    const int bid   = blockIdx.x;
    const int bp    = bid >> 3;
    const int chunk = bid & 7;
    const int p     = bp & 15;
    const int b     = bp >> 4;
    const int tid   = threadIdx.x;
    const int lane  = tid & 63;
    const int wave  = tid >> 6;

    {
        const float* s3 = sp + (size_t)(bp*NS)*3;
        float x = s3[tid*3+0], y = s3[tid*3+1], z = s3[tid*3+2];
        lspx[tid] = x; lspy[tid] = y; lspz[tid] = z;
        lspw[tid] = x*x + y*y + z*z;
        const float* q3 = pts + (size_t)(b*NN + chunk*CHUNK)*3;
#pragma unroll
        for (int k = 0; k < 2; ++k) {
            int i = tid + k*256;
            float qx = q3[i*3+0], qy = q3[i*3+1], qz = q3[i*3+2];
            lptx[i] = -2.0f*qx; lpty[i] = -2.0f*qy; lptz[i] = -2.0f*qz;
            lptw[i] = qx*qx + qy*qy + qz*qz;
        }
    }
    __syncthreads();

    // ---- Phase 1: s-quarter split (g==wave), 8 n/thread; min over 64 s of (a2-2ab) ----
    {
        const int g  = tid >> 6;
        const int nl = tid & 63;
        float qx[8], qy[8], qz[8], mn[8];
#pragma unroll
        for (int k = 0; k < 8; ++k) {
            int i = nl + k*64;
            qx[k] = lptx[i]; qy[k] = lpty[i]; qz[k] = lptz[i];
            mn[k] = INFINITY;
        }
        const int sb = g*64;
#pragma unroll 2
        for (int s = 0; s < 64; s += 2) {
            f32x2 vx = *(const f32x2*)&lspx[sb+s];
            f32x2 vy = *(const f32x2*)&lspy[sb+s];
            f32x2 vz = *(const f32x2*)&lspz[sb+s];
            f32x2 vw = *(const f32x2*)&lspw[sb+s];
#pragma unroll
            for (int k = 0; k < 8; ++k) {
                f32x2 gg = pkfma(sp2(qx[k]), vx,
                           pkfma(sp2(qy[k]), vy,
                           pkfma(sp2(qz[k]), vz, vw)));
                mn[k] = fminf(fminf(gg.x, gg.y), mn[k]);
            }
        }
#pragma unroll
        for (int k = 0; k < 8; ++k) pm1[g][nl + k*64] = mn[k];
    }

    // ---- Phase 2: 8 s/thread, n-eighth split; min over 64 n of (b2-2ab) ----
    {
        const int sg   = tid & 31;
        const int nsub = tid >> 5;
        float ax[8], ay[8], az[8], m[8];
#pragma unroll
        for (int j = 0; j < 8; ++j) {
            int s = sg + j*32;
            ax[j] = lspx[s]; ay[j] = lspy[s]; az[j] = lspz[s];
            m[j] = INFINITY;
        }
        const int nb = nsub*64;
#pragma unroll 2
        for (int n = 0; n < 64; n += 2) {
            f32x2 ux = *(const f32x2*)&lptx[nb+n];
            f32x2 uy = *(const f32x2*)&lpty[nb+n];
            f32x2 uz = *(const f32x2*)&lptz[nb+n];
            f32x2 uw = *(const f32x2*)&lptw[nb+n];
#pragma unroll
            for (int j = 0; j < 8; ++j) {
                f32x2 gg = pkfma(ux, sp2(ax[j]),
                           pkfma(uy, sp2(ay[j]),
                           pkfma(uz, sp2(az[j]), uw)));
                m[j] = fminf(fminf(gg.x, gg.y), m[j]);
            }
        }
#pragma unroll
        for (int j = 0; j < 8; ++j) pm2[nsub][sg + j*32] = m[j];
    }
    __syncthreads();

    {
        float mm = fminf(fminf(fminf(pm2[0][tid], pm2[1][tid]),
                               fminf(pm2[2][tid], pm2[3][tid])),
                         fminf(fminf(pm2[4][tid], pm2[5][tid]),
                               fminf(pm2[6][tid], pm2[7][tid])));
        minw[(size_t)bid*NS + tid] = fmaxf(mm + lspw[tid], 0.0f);
    }

    float acc = 0.0f;
#pragma unroll
    for (int j = 0; j < 2; ++j) {
        int n = tid + j*256;
        float mm = fminf(fminf(pm1[0][n], pm1[1][n]),
                         fminf(pm1[2][n], pm1[3][n]));
        float d  = fmaxf(mm + lptw[n], 0.0f);
        acc += d * assign[(size_t)(b*NN + chunk*CHUNK + n)*NP + p];
    }
#pragma unroll
    for (int msk = 32; msk >= 1; msk >>= 1)
        acc += __shfl_xor(acc, msk, 64);
    if (lane == 0) psum[wave] = acc;
    __syncthreads();
    if (tid == 0) partials[bid] = psum[0] + psum[1] + psum[2] + psum[3];
}

// tail + final merged; reset-free mod-NBP gate (works with any initial cnt value,
// idempotent across graph replays, order-independent -> deterministic)
__global__ __launch_bounds__(256) void sqreg_tail(
    const float* __restrict__ minw,     // (NBLK, S)
    const float* __restrict__ partials, // NBLK
    const float* __restrict__ exist,    // (B,P)
    float* __restrict__ s2p,            // NBP
    float* __restrict__ pp,             // NBP
    unsigned int* __restrict__ cnt,
    float* __restrict__ out)
{
    __shared__ float wsum[4];
    __shared__ float ppw[2];
    __shared__ float fin[8];
    __shared__ unsigned int sflag;
    const int bp   = blockIdx.x;
    const int tid  = threadIdx.x;
    const int lane = tid & 63;
    const int wave = tid >> 6;

    // per-bp reduction: min over chunks, sum over s
    const float* base = minw + (size_t)(bp*NCHUNK)*NS + tid;
    float m = base[0];
#pragma unroll
    for (int c = 1; c < NCHUNK; ++c) m = fminf(m, base[(size_t)c*NS]);
#pragma unroll
    for (int msk = 32; msk >= 1; msk >>= 1)
        m += __shfl_xor(m, msk, 64);
    if (lane == 0) wsum[wave] = m;
    __syncthreads();

    if (tid == 0) {
        s2p[bp] = (wsum[0] + wsum[1] + wsum[2] + wsum[3]) * (1.0f/(float)NS);
        float a = 0.0f;
#pragma unroll
        for (int c = 0; c < NCHUNK; ++c) a += partials[bp*NCHUNK + c];
        pp[bp] = a;
        __threadfence();                                   // release s2p/pp
        sflag = ((atomicAdd(cnt, 1u) % (unsigned)NBP) == (unsigned)(NBP-1)) ? 1u : 0u;
    }
    __syncthreads();
    if (sflag == 0u) return;

    // ---- last-finishing block: scalar tail ----
    __threadfence();                                       // acquire
    const volatile float* vs2p = s2p;
    const volatile float* vpp  = pp;

    float tsum = (tid < NBP) ? vpp[tid] : 0.0f;
#pragma unroll
    for (int msk = 32; msk >= 1; msk >>= 1)
        tsum += __shfl_xor(tsum, msk, 64);
    if (tid == 0)  ppw[0] = tsum;
    if (tid == 64) ppw[1] = tsum;

    if (tid < NBP) {                   // group of 16 lanes = one b
        float e  = exist[tid];
        float sv = vs2p[tid] * e;
#pragma unroll
        for (int msk = 8; msk >= 1; msk >>= 1) {
            e  += __shfl_xor(e,  msk, 64);
            sv += __shfl_xor(sv, msk, 64);
        }
        if ((tid & 15) == 0) fin[tid >> 4] = sv / fmaxf(e, EPSV);
    }
    __syncthreads();

    if (tid == 0) {
        float sq = 0.0f;
#pragma unroll
        for (int g = 0; g < NB; ++g) sq += fin[g];
        out[0] = (ppw[0] + ppw[1]) / (float)(NB*NN) + sq * (1.0f/(float)NB);
    }
}

extern "C" void kernel_launch(void* const* d_in, const int* in_sizes, int n_in,
                              void* d_out, int out_size, void* d_ws, size_t ws_size,
                              hipStream_t stream) {
    const float* sp     = (const float*)d_in[0];
    const float* pts    = (const float*)d_in[1];
    const float* assign = (const float*)d_in[2];
    const float* exist  = (const float*)d_in[3];
    float* out = (float*)d_out;

    char* ws = (char*)d_ws;
    float*        minw = (float*)(ws);
    float*        part = (float*)(ws + 0x100000);
    float*        s2p  = (float*)(ws + 0x101000);
    float*        pp   = (float*)(ws + 0x101200);
    unsigned int* cnt  = (unsigned int*)(ws + 0x101400);

    sqreg_main<<<NBLK, 256, 0, stream>>>(sp, pts, assign, minw, part);
    sqreg_tail<<<NBP,  256, 0, stream>>>(minw, part, exist, s2p, pp, cnt, out);
}

// Round 11
// 28.949 us; speedup vs baseline: 1.1719x; 1.1436x over previous
//
#include <hip/hip_runtime.h>

#define NB 8
#define NP 16
#define NS 256
#define NN 4096
#define NBP (NB*NP)             // 128
#define NCHUNK 8
#define CHUNK (NN/NCHUNK)       // 512 n per block
#define NBLK (NBP*NCHUNK)       // 1024
#define EPSV 1e-6f

typedef _Float16 half8 __attribute__((ext_vector_type(8)));
typedef float    f32x4 __attribute__((ext_vector_type(4)));

#define H0 ((_Float16)0.0f)
#define H1 ((_Float16)1.0f)

// ---------------- workspace layout (bytes) ----------------
// minw : float[NBLK*NS]  @ 0          (1 MB)
// part : float[NBLK]     @ 0x100000
// s2p  : float[NBP]      @ 0x101000
// pp   : float[NBP]      @ 0x101200

// d2(s,n) = |a_s|^2 + |b_n|^2 - 2 a_s.b_n, computed on the matrix pipe as a
// K=13 inner product with hi/lo f16 splits (error ~1e-5):
//   A row s : [xh,xh,xl,yh,yh,yl,zh,zh | zl,a2h,a2l,1,1,0,0,0]
//   B col n : [txh,txl,txh,tyh,tyl,tyh,tzh,tzl | tzh,1,1,b2h,b2l,0,0,0]
// where t* = -2*b coords. A/B fragment map (16x16x32): lane l holds
// row/col = l&15, k = (l>>4)*8 + j.  C/D: col=lane&15, row=(lane>>4)*4+reg.

__global__ __launch_bounds__(256) void sqreg_main(
    const float* __restrict__ sp,     // (B,P,S,3)
    const float* __restrict__ pts,    // (B,N,3)
    const float* __restrict__ assign, // (B,N,P)
    float* __restrict__ minw,         // (NBLK, S)
    float* __restrict__ partials)     // NBLK
{
    __shared__ __align__(16) _Float16 lsa[NS][16];     // 8 KB
    __shared__ __align__(16) _Float16 lpb[CHUNK][16];  // 16 KB
    __shared__ float pm1[4][CHUNK];                    // 8 KB
    __shared__ float psum[4];

    const int bid   = blockIdx.x;
    const int bp    = bid >> 3;
    const int chunk = bid & 7;
    const int p     = bp & 15;
    const int b     = bp >> 4;
    const int tid   = threadIdx.x;
    const int lane  = tid & 63;
    const int wave  = tid >> 6;
    const int l15   = lane & 15;
    const int lg    = lane >> 4;

    // ---- stage: f32 -> hi/lo f16 fragment rows ----
    {
        const float* s3 = sp + (size_t)(bp*NS)*3;
        float x = s3[tid*3+0], y = s3[tid*3+1], z = s3[tid*3+2];
        float a2 = x*x + y*y + z*z;
        _Float16 xh=(_Float16)x, yh=(_Float16)y, zh=(_Float16)z, ah=(_Float16)a2;
        _Float16 xl=(_Float16)(x-(float)xh), yl=(_Float16)(y-(float)yh);
        _Float16 zl=(_Float16)(z-(float)zh), al=(_Float16)(a2-(float)ah);
        half8 lo = {xh,xh,xl,yh,yh,yl,zh,zh};
        half8 hi = {zl,ah,al,H1,H1,H0,H0,H0};
        *(half8*)&lsa[tid][0] = lo;
        *(half8*)&lsa[tid][8] = hi;

        const float* q3 = pts + (size_t)(b*NN + chunk*CHUNK)*3;
#pragma unroll
        for (int k = 0; k < 2; ++k) {
            int i = tid + k*256;
            float bx = q3[i*3+0], by = q3[i*3+1], bz = q3[i*3+2];
            float tx = -2.0f*bx, ty = -2.0f*by, tz = -2.0f*bz;
            float b2 = bx*bx + by*by + bz*bz;
            _Float16 txh=(_Float16)tx, tyh=(_Float16)ty, tzh=(_Float16)tz, bh=(_Float16)b2;
            _Float16 txl=(_Float16)(tx-(float)txh), tyl=(_Float16)(ty-(float)tyh);
            _Float16 tzl=(_Float16)(tz-(float)tzh), bl=(_Float16)(b2-(float)bh);
            half8 blo = {txh,txl,txh,tyh,tyl,tyh,tzh,tzl};
            half8 bhi = {tzh,H1,H1,bh,bl,H0,H0,H0};
            *(half8*)&lpb[i][0] = blo;
            *(half8*)&lpb[i][8] = bhi;
        }
    }
    __syncthreads();

    // ---- A fragments: wave owns s in [wave*64, wave*64+64) ----
    half8 afrag[4];
#pragma unroll
    for (int st = 0; st < 4; ++st) {
        half8 t = {H0,H0,H0,H0,H0,H0,H0,H0};
        if (lane < 32)
            t = *(const half8*)&lsa[wave*64 + st*16 + l15][(lane>>4)*8];
        afrag[st] = t;
    }

    f32x4 rmin[4];
#pragma unroll
    for (int st = 0; st < 4; ++st)
        rmin[st] = (f32x4){INFINITY, INFINITY, INFINITY, INFINITY};

    // ---- MFMA sweep: 32 n-tiles x 4 s-tiles; both reductions from one tile ----
#pragma unroll 2
    for (int nt = 0; nt < 32; ++nt) {
        half8 bf = {H0,H0,H0,H0,H0,H0,H0,H0};
        if (lane < 32)
            bf = *(const half8*)&lpb[nt*16 + l15][(lane>>4)*8];

        f32x4 acc[4];
#pragma unroll
        for (int st = 0; st < 4; ++st)
            acc[st] = __builtin_amdgcn_mfma_f32_16x16x32_f16(
                afrag[st], bf, (f32x4){0.f,0.f,0.f,0.f}, 0, 0, 0);

        float cm = INFINITY;
#pragma unroll
        for (int st = 0; st < 4; ++st) {
            rmin[st][0] = fminf(rmin[st][0], acc[st][0]);
            rmin[st][1] = fminf(rmin[st][1], acc[st][1]);
            rmin[st][2] = fminf(rmin[st][2], acc[st][2]);
            rmin[st][3] = fminf(rmin[st][3], acc[st][3]);
            cm = fminf(cm, fminf(fminf(acc[st][0], acc[st][1]),
                                 fminf(acc[st][2], acc[st][3])));
        }
        cm = fminf(cm, __shfl_xor(cm, 16, 64));   // combine 4 row-groups
        cm = fminf(cm, __shfl_xor(cm, 32, 64));
        if (lane < 16) pm1[wave][nt*16 + lane] = cm;   // min over this wave's 64 s
    }

    // ---- epilogue: min-over-n (cross-col reduce) -> minw ----
#pragma unroll
    for (int st = 0; st < 4; ++st) {
#pragma unroll
        for (int r = 0; r < 4; ++r) {
            float v = rmin[st][r];
            v = fminf(v, __shfl_xor(v, 1, 64));
            v = fminf(v, __shfl_xor(v, 2, 64));
            v = fminf(v, __shfl_xor(v, 4, 64));
            v = fminf(v, __shfl_xor(v, 8, 64));
            if (l15 == 0)
                minw[(size_t)bid*NS + wave*64 + st*16 + lg*4 + r] = fmaxf(v, 0.0f);
        }
    }
    __syncthreads();

    // ---- phase-1 combine: min over 4 waves' s-partials, weight, reduce ----
    float acc = 0.0f;
#pragma unroll
    for (int j = 0; j < 2; ++j) {
        int n = tid + j*256;
        float mm = fminf(fminf(pm1[0][n], pm1[1][n]),
                         fminf(pm1[2][n], pm1[3][n]));
        float d  = fmaxf(mm, 0.0f);
        acc += d * assign[(size_t)(b*NN + chunk*CHUNK + n)*NP + p];
    }
#pragma unroll
    for (int msk = 32; msk >= 1; msk >>= 1)
        acc += __shfl_xor(acc, msk, 64);
    if (lane == 0) psum[wave] = acc;
    __syncthreads();
    if (tid == 0) partials[bid] = psum[0] + psum[1] + psum[2] + psum[3];
}

__global__ __launch_bounds__(256) void sqreg_tail(
    const float* __restrict__ minw,     // (NBLK, S)
    const float* __restrict__ partials, // NBLK
    float* __restrict__ s2p,            // NBP
    float* __restrict__ pp)             // NBP
{
    __shared__ float wsum[4];
    const int bp   = blockIdx.x;
    const int tid  = threadIdx.x;
    const int lane = tid & 63;
    const int wave = tid >> 6;

    const float* base = minw + (size_t)(bp*NCHUNK)*NS + tid;
    float m = base[0];
#pragma unroll
    for (int c = 1; c < NCHUNK; ++c) m = fminf(m, base[(size_t)c*NS]);
#pragma unroll
    for (int msk = 32; msk >= 1; msk >>= 1)
        m += __shfl_xor(m, msk, 64);
    if (lane == 0) wsum[wave] = m;
    __syncthreads();

    if (tid == 0) {
        s2p[bp] = (wsum[0] + wsum[1] + wsum[2] + wsum[3]) * (1.0f/(float)NS);
        float a = 0.0f;
#pragma unroll
        for (int c = 0; c < NCHUNK; ++c) a += partials[bp*NCHUNK + c];
        pp[bp] = a;
    }
}

__global__ __launch_bounds__(256) void sqreg_final(
    const float* __restrict__ s2p,
    const float* __restrict__ pp,
    const float* __restrict__ exist,   // (B,P)
    float* __restrict__ out)
{
    __shared__ float ppw[2];
    __shared__ float fin[8];
    const int tid = threadIdx.x;

    float tsum = (tid < NBP) ? pp[tid] : 0.0f;
#pragma unroll
    for (int msk = 32; msk >= 1; msk >>= 1)
        tsum += __shfl_xor(tsum, msk, 64);
    if (tid == 0)  ppw[0] = tsum;
    if (tid == 64) ppw[1] = tsum;

    if (tid < NBP) {                   // group of 16 lanes = one b
        float e  = exist[tid];
        float sv = s2p[tid] * e;
#pragma unroll
        for (int msk = 8; msk >= 1; msk >>= 1) {
            e  += __shfl_xor(e,  msk, 64);
            sv += __shfl_xor(sv, msk, 64);
        }
        if ((tid & 15) == 0) fin[tid >> 4] = sv / fmaxf(e, EPSV);
    }
    __syncthreads();

    if (tid == 0) {
        float sq = 0.0f;
#pragma unroll
        for (int g = 0; g < NB; ++g) sq += fin[g];
        out[0] = (ppw[0] + ppw[1]) / (float)(NB*NN) + sq * (1.0f/(float)NB);
    }
}

extern "C" void kernel_launch(void* const* d_in, const int* in_sizes, int n_in,
                              void* d_out, int out_size, void* d_ws, size_t ws_size,
                              hipStream_t stream) {
    const float* sp     = (const float*)d_in[0];
    const float* pts    = (const float*)d_in[1];
    const float* assign = (const float*)d_in[2];
    const float* exist  = (const float*)d_in[3];
    float* out = (float*)d_out;

    char* ws = (char*)d_ws;
    float* minw = (float*)(ws);
    float* part = (float*)(ws + 0x100000);
    float* s2p  = (float*)(ws + 0x101000);
    float* pp   = (float*)(ws + 0x101200);

    sqreg_main <<<NBLK, 256, 0, stream>>>(sp, pts, assign, minw, part);
    sqreg_tail <<<NBP,  256, 0, stream>>>(minw, part, s2p, pp);
    sqreg_final<<<1,    256, 0, stream>>>(s2p, pp, exist, out);
}